// Round 7
// baseline (70.638 us; speedup 1.0000x reference)
//
#include <hip/hip_runtime.h>
#include <math.h>

#define LSEQ 4096
#define NK 512
#define NB 16

template <int KS>
__device__ __forceinline__ void rocket_body(
    const float* __restrict__ sx0,   // LDS x row: sx0[j] = x[j]
    const float* __restrict__ sx1,   // LDS shifted: sx1[j] = x[j+1]
    const float* __restrict__ xg,    // global x row
    const float* __restrict__ w, const float* __restrict__ bias,
    const int* __restrict__ off, const int* __restrict__ lout,
    int P, int li, int b, int outj,
    float* __restrict__ out, float* smx, int* scnt)
{
    const int tid = threadIdx.x;

    float wk[KS];
#pragma unroll
    for (int k = 0; k < KS; ++k) wk[k] = w[li * KS + k];
    const int o0  = off[li * KS + 0];
    const int o1  = off[li * KS + 1];
    const int d   = o1 - o0;          // dilation
    const int pad = P - o0;           // doubled pad
    const float bi = bias[li];
    const int   Lo = lout[li];

    // interior: all taps idx = t - pad + k*d in [0, LSEQ)
    int t_lo = min(pad, Lo);
    int t_hi = min(Lo, LSEQ - (KS - 1) * d + pad);
    if (t_hi < t_lo) t_hi = t_lo;
    // quad-aligned interior
    int T0 = (t_lo + 3) & ~3;
    int T1 = t_hi & ~3;
    if (T1 < T0) { T0 = 0; T1 = 0; }   // degenerate: edges cover everything

    float mx  = -INFINITY;
    int   cnt = 0;

    // ---- left edge [0, T0): bounds-checked global taps ----
    for (int t = tid; t < T0; t += 256) {
        float y = bi;
        int idx = t - pad;
#pragma unroll
        for (int k = 0; k < KS; ++k) {
            float xv = ((unsigned)idx < (unsigned)LSEQ) ? xg[idx] : 0.0f;
            y = fmaf(wk[k], xv, y);
            idx += d;
        }
        mx = fmaxf(mx, y); cnt += (y > 0.0f);
    }

    // ---- interior quads [T0, T1): LDS (even k) + global (odd k), G=4 ----
    const int nq = (T1 - T0) >> 2;
    for (int q = tid; q < nq; q += 256) {
        const int t = T0 + 4 * q;      // t ≡ T0 (mod 4), T0 ≡ 0 (mod 4)
        float X[KS][4];
#pragma unroll
        for (int k = 0; k < KS; ++k) {
            const int A = t - pad + k * d;   // quad start, in [0, LSEQ-4]
            if (k & 1) {
                // global path: alignment class r = A mod 4 (block-uniform)
                const int r = (T0 - pad + k * d) & 3;
                const float* a = xg + A;
                if (r == 0) {
                    const float4 v = *(const float4*)a;
                    X[k][0] = v.x; X[k][1] = v.y; X[k][2] = v.z; X[k][3] = v.w;
                } else if (r == 2) {
                    const float2 v0 = *(const float2*)a;
                    const float2 v1 = *(const float2*)(a + 2);
                    X[k][0] = v0.x; X[k][1] = v0.y; X[k][2] = v1.x; X[k][3] = v1.y;
                } else {
                    const float2 v = *(const float2*)(a + 1);
                    X[k][0] = a[0]; X[k][1] = v.x; X[k][2] = v.y; X[k][3] = a[3];
                }
            } else {
                // LDS path: parity of A is block-uniform
                if (((k * d + pad) & 1) == 0) {        // A even
                    const float2 v0 = *(const float2*)(sx0 + A);
                    const float2 v1 = *(const float2*)(sx0 + A + 2);
                    X[k][0] = v0.x; X[k][1] = v0.y; X[k][2] = v1.x; X[k][3] = v1.y;
                } else {                                // A odd: use shifted copy
                    const float2 v0 = *(const float2*)(sx1 + A - 1);
                    const float2 v1 = *(const float2*)(sx1 + A + 1);
                    X[k][0] = v0.x; X[k][1] = v0.y; X[k][2] = v1.x; X[k][3] = v1.y;
                }
            }
        }
        float y0 = bi, y1 = bi, y2 = bi, y3 = bi;
#pragma unroll
        for (int k = 0; k < KS; ++k) {
            y0 = fmaf(wk[k], X[k][0], y0);
            y1 = fmaf(wk[k], X[k][1], y1);
            y2 = fmaf(wk[k], X[k][2], y2);
            y3 = fmaf(wk[k], X[k][3], y3);
        }
        mx = fmaxf(mx, y0); cnt += (y0 > 0.0f);
        mx = fmaxf(mx, y1); cnt += (y1 > 0.0f);
        mx = fmaxf(mx, y2); cnt += (y2 > 0.0f);
        mx = fmaxf(mx, y3); cnt += (y3 > 0.0f);
    }

    // ---- right edge [T1, Lo): bounds-checked global taps ----
    for (int t = T1 + tid; t < Lo; t += 256) {
        float y = bi;
        int idx = t - pad;
#pragma unroll
        for (int k = 0; k < KS; ++k) {
            float xv = ((unsigned)idx < (unsigned)LSEQ) ? xg[idx] : 0.0f;
            y = fmaf(wk[k], xv, y);
            idx += d;
        }
        mx = fmaxf(mx, y); cnt += (y > 0.0f);
    }

    // ---- wave64 + block reduction ----
#pragma unroll
    for (int o = 32; o > 0; o >>= 1) {
        mx = fmaxf(mx, __shfl_down(mx, o, 64));
        cnt += __shfl_down(cnt, o, 64);
    }
    const int wid = tid >> 6;
    if ((tid & 63) == 0) { smx[wid] = mx; scnt[wid] = cnt; }
    __syncthreads();
    if (tid == 0) {
        float m = smx[0]; int c = scnt[0];
#pragma unroll
        for (int i = 1; i < 4; ++i) { m = fmaxf(m, smx[i]); c += scnt[i]; }
        out[b * (2 * NK) + 2 * outj]     = m;
        out[b * (2 * NK) + 2 * outj + 1] = (float)c / (float)Lo;
    }
}

__global__ __launch_bounds__(256, 4) void rocket_hybrid_kernel(
    const float* __restrict__ x, const int* __restrict__ perm,
    const int* __restrict__ Pp,
    const float* __restrict__ w0, const float* __restrict__ b0,
    const int* __restrict__ off0, const int* __restrict__ l0,
    const float* __restrict__ w1, const float* __restrict__ b1,
    const int* __restrict__ off1, const int* __restrict__ l1,
    const float* __restrict__ w2, const float* __restrict__ b2,
    const int* __restrict__ off2, const int* __restrict__ l2,
    int n0, int n01,
    float* __restrict__ out)
{
    __shared__ float sx0[LSEQ];
    __shared__ float sx1[LSEQ];
    __shared__ int   sj;
    __shared__ float smx[4];
    __shared__ int   scnt[4];

    const int gid = blockIdx.x;
    const int b   = blockIdx.y;
    const int tid = threadIdx.x;

    // inverse permutation: sj = j with perm[j] == gid
    if (perm[tid]       == gid) sj = tid;
    if (perm[tid + 256] == gid) sj = tid + 256;

    // stage x row: sx0[j]=x[j], sx1[j]=x[j+1] (sx1[LSEQ-1] unwritten, never read)
    const float* xg = x + (size_t)b * LSEQ;
    const float4* x4 = (const float4*)xg;
#pragma unroll
    for (int i = 0; i < LSEQ / 4 / 256; ++i) {
        const int e4 = tid + 256 * i;
        const float4 v = x4[e4];
        const int e = 4 * e4;
        *(float4*)(sx0 + e) = v;
        if (e > 0) sx1[e - 1] = v.x;
        sx1[e]     = v.y;
        sx1[e + 1] = v.z;
        sx1[e + 2] = v.w;
    }
    __syncthreads();

    const int P = *Pp;
    const int outj = sj;

    if (gid < n0) {
        rocket_body<7>(sx0, sx1, xg, w0, b0, off0, l0, P, gid, b, outj, out, smx, scnt);
    } else if (gid < n01) {
        rocket_body<9>(sx0, sx1, xg, w1, b1, off1, l1, P, gid - n0, b, outj, out, smx, scnt);
    } else {
        rocket_body<11>(sx0, sx1, xg, w2, b2, off2, l2, P, gid - n01, b, outj, out, smx, scnt);
    }
}

extern "C" void kernel_launch(void* const* d_in, const int* in_sizes, int n_in,
                              void* d_out, int out_size, void* d_ws, size_t ws_size,
                              hipStream_t stream) {
    const float* x    = (const float*)d_in[0];
    const int*   perm = (const int*)d_in[1];
    const int*   Pp   = (const int*)d_in[2];
    const float* w0   = (const float*)d_in[3];
    const float* b0   = (const float*)d_in[4];
    const int*   off0 = (const int*)d_in[5];
    const int*   l0   = (const int*)d_in[6];
    const float* w1   = (const float*)d_in[7];
    const float* b1   = (const float*)d_in[8];
    const int*   off1 = (const int*)d_in[9];
    const int*   l1   = (const int*)d_in[10];
    const float* w2   = (const float*)d_in[11];
    const float* b2   = (const float*)d_in[12];
    const int*   off2 = (const int*)d_in[13];
    const int*   l2   = (const int*)d_in[14];

    const int n0 = in_sizes[4];
    const int n1 = in_sizes[8];

    float* out = (float*)d_out;

    rocket_hybrid_kernel<<<dim3(NK, NB), 256, 0, stream>>>(
        x, perm, Pp, w0, b0, off0, l0, w1, b1, off1, l1, w2, b2, off2, l2,
        n0, n0 + n1, out);
}

// Round 8
// 63.351 us; speedup vs baseline: 1.1150x; 1.1150x over previous
//
#include <hip/hip_runtime.h>
#include <math.h>

#define LSEQ 4096
#define NK 512
#define NB 16

template <int KS>
__device__ __forceinline__ void rocket_body(
    const float* __restrict__ sx0,   // LDS x row: sx0[j] = x[j]
    const float* __restrict__ sx1,   // LDS shifted: sx1[j] = x[j+1]
    const float* __restrict__ xg,    // global x row
    const float* __restrict__ w, const float* __restrict__ bias,
    const int* __restrict__ off, const int* __restrict__ lout,
    int P, int li, int b, int outj,
    float* __restrict__ out, float* smx, int* scnt)
{
    const int tid = threadIdx.x;

    float wk[KS];
#pragma unroll
    for (int k = 0; k < KS; ++k) wk[k] = w[li * KS + k];
    const int o0  = off[li * KS + 0];
    const int o1  = off[li * KS + 1];
    const int d   = o1 - o0;          // dilation
    const int pad = P - o0;           // doubled pad
    const float bi = bias[li];
    const int   Lo = lout[li];

    // interior: all taps idx = t - pad + k*d in [0, LSEQ)
    int t_lo = min(pad, Lo);
    int t_hi = min(Lo, LSEQ - (KS - 1) * d + pad);
    if (t_hi < t_lo) t_hi = t_lo;
    // quad-aligned interior
    int T0 = (t_lo + 3) & ~3;
    int T1 = t_hi & ~3;
    if (T1 < T0) { T0 = 0; T1 = 0; }   // degenerate: edges cover everything

    float mx  = -INFINITY;
    int   cnt = 0;

    // ---- left edge [0, T0): LDS clamp + select-zero ----
    for (int t = tid; t < T0; t += 256) {
        float y = bi;
        int idx = t - pad;
#pragma unroll
        for (int k = 0; k < KS; ++k) {
            int ic = min(max(idx, 0), LSEQ - 1);
            float xv = sx0[ic];
            xv = ((unsigned)idx < (unsigned)LSEQ) ? xv : 0.0f;
            y = fmaf(wk[k], xv, y);
            idx += d;
        }
        mx = fmaxf(mx, y); cnt += (y > 0.0f);
    }

    // ---- interior quads [T0, T1): DS pipe (A%4==0,1) + L1 pipe (A%4==2,3) ----
    const int nq = (T1 - T0) >> 2;
    for (int q = tid; q < nq; q += 256) {
        const int t = T0 + 4 * q;      // t ≡ 0 (mod 4)
        float X[KS][4];
#pragma unroll
        for (int k = 0; k < KS; ++k) {
            const int A = t - pad + k * d;           // quad start
            const int r = (T0 - pad + k * d) & 3;    // block-uniform class
            if (r == 0) {
                const float4 v = *(const float4*)(sx0 + A);          // 16B aligned
                X[k][0] = v.x; X[k][1] = v.y; X[k][2] = v.z; X[k][3] = v.w;
            } else if (r == 1) {
                const float4 v = *(const float4*)(sx1 + (A - 1));    // 16B aligned
                X[k][0] = v.x; X[k][1] = v.y; X[k][2] = v.z; X[k][3] = v.w;
            } else if (r == 2) {
                const float* a = xg + A;
                const float2 v0 = *(const float2*)a;                 // 8B aligned
                const float2 v1 = *(const float2*)(a + 2);
                X[k][0] = v0.x; X[k][1] = v0.y; X[k][2] = v1.x; X[k][3] = v1.y;
            } else {
                const float* a = xg + A;
                const float2 v = *(const float2*)(a + 1);            // 8B aligned
                X[k][0] = a[0]; X[k][1] = v.x; X[k][2] = v.y; X[k][3] = a[3];
            }
        }
        float y0 = bi, y1 = bi, y2 = bi, y3 = bi;
#pragma unroll
        for (int k = 0; k < KS; ++k) {
            y0 = fmaf(wk[k], X[k][0], y0);
            y1 = fmaf(wk[k], X[k][1], y1);
            y2 = fmaf(wk[k], X[k][2], y2);
            y3 = fmaf(wk[k], X[k][3], y3);
        }
        mx = fmaxf(mx, y0); cnt += (y0 > 0.0f);
        mx = fmaxf(mx, y1); cnt += (y1 > 0.0f);
        mx = fmaxf(mx, y2); cnt += (y2 > 0.0f);
        mx = fmaxf(mx, y3); cnt += (y3 > 0.0f);
    }

    // ---- right edge [T1, Lo): LDS clamp + select-zero ----
    for (int t = T1 + tid; t < Lo; t += 256) {
        float y = bi;
        int idx = t - pad;
#pragma unroll
        for (int k = 0; k < KS; ++k) {
            int ic = min(max(idx, 0), LSEQ - 1);
            float xv = sx0[ic];
            xv = ((unsigned)idx < (unsigned)LSEQ) ? xv : 0.0f;
            y = fmaf(wk[k], xv, y);
            idx += d;
        }
        mx = fmaxf(mx, y); cnt += (y > 0.0f);
    }

    // ---- wave64 + block reduction ----
#pragma unroll
    for (int o = 32; o > 0; o >>= 1) {
        mx = fmaxf(mx, __shfl_down(mx, o, 64));
        cnt += __shfl_down(cnt, o, 64);
    }
    const int wid = tid >> 6;
    if ((tid & 63) == 0) { smx[wid] = mx; scnt[wid] = cnt; }
    __syncthreads();
    if (tid == 0) {
        float m = smx[0]; int c = scnt[0];
#pragma unroll
        for (int i = 1; i < 4; ++i) { m = fmaxf(m, smx[i]); c += scnt[i]; }
        out[b * (2 * NK) + 2 * outj]     = m;
        out[b * (2 * NK) + 2 * outj + 1] = (float)c / (float)Lo;
    }
}

__global__ __launch_bounds__(256, 4) void rocket_split_kernel(
    const float* __restrict__ x, const int* __restrict__ perm,
    const int* __restrict__ Pp,
    const float* __restrict__ w0, const float* __restrict__ b0,
    const int* __restrict__ off0, const int* __restrict__ l0,
    const float* __restrict__ w1, const float* __restrict__ b1,
    const int* __restrict__ off1, const int* __restrict__ l1,
    const float* __restrict__ w2, const float* __restrict__ b2,
    const int* __restrict__ off2, const int* __restrict__ l2,
    int n0, int n01,
    float* __restrict__ out)
{
    __shared__ float sx0[LSEQ];
    __shared__ float sx1[LSEQ];
    __shared__ int   sj;
    __shared__ float smx[4];
    __shared__ int   scnt[4];

    const int gid = blockIdx.x;
    const int b   = blockIdx.y;
    const int tid = threadIdx.x;

    // inverse permutation: sj = j with perm[j] == gid
    if (perm[tid]       == gid) sj = tid;
    if (perm[tid + 256] == gid) sj = tid + 256;

    // stage x row: sx0[j]=x[j], sx1[j]=x[j+1] (sx1[LSEQ-1] unwritten, never read)
    const float* xg = x + (size_t)b * LSEQ;
    const float4* x4 = (const float4*)xg;
#pragma unroll
    for (int i = 0; i < LSEQ / 4 / 256; ++i) {
        const int e4 = tid + 256 * i;
        const float4 v = x4[e4];
        const int e = 4 * e4;
        *(float4*)(sx0 + e) = v;
        if (e > 0) sx1[e - 1] = v.x;
        sx1[e]     = v.y;
        sx1[e + 1] = v.z;
        sx1[e + 2] = v.w;
    }
    __syncthreads();

    const int P = *Pp;
    const int outj = sj;

    if (gid < n0) {
        rocket_body<7>(sx0, sx1, xg, w0, b0, off0, l0, P, gid, b, outj, out, smx, scnt);
    } else if (gid < n01) {
        rocket_body<9>(sx0, sx1, xg, w1, b1, off1, l1, P, gid - n0, b, outj, out, smx, scnt);
    } else {
        rocket_body<11>(sx0, sx1, xg, w2, b2, off2, l2, P, gid - n01, b, outj, out, smx, scnt);
    }
}

extern "C" void kernel_launch(void* const* d_in, const int* in_sizes, int n_in,
                              void* d_out, int out_size, void* d_ws, size_t ws_size,
                              hipStream_t stream) {
    const float* x    = (const float*)d_in[0];
    const int*   perm = (const int*)d_in[1];
    const int*   Pp   = (const int*)d_in[2];
    const float* w0   = (const float*)d_in[3];
    const float* b0   = (const float*)d_in[4];
    const int*   off0 = (const int*)d_in[5];
    const int*   l0   = (const int*)d_in[6];
    const float* w1   = (const float*)d_in[7];
    const float* b1   = (const float*)d_in[8];
    const int*   off1 = (const int*)d_in[9];
    const int*   l1   = (const int*)d_in[10];
    const float* w2   = (const float*)d_in[11];
    const float* b2   = (const float*)d_in[12];
    const int*   off2 = (const int*)d_in[13];
    const int*   l2   = (const int*)d_in[14];

    const int n0 = in_sizes[4];
    const int n1 = in_sizes[8];

    float* out = (float*)d_out;

    rocket_split_kernel<<<dim3(NK, NB), 256, 0, stream>>>(
        x, perm, Pp, w0, b0, off0, l0, w1, b1, off1, l1, w2, b2, off2, l2,
        n0, n0 + n1, out);
}